// Round 13
// baseline (736.305 us; speedup 1.0000x reference)
//
#include <hip/hip_runtime.h>

#define NNZC   1000000
#define NPOI   100000
#define NEDGE  50000
#define NUSER  50000
#define DIM    128
#define NL     3

#define PB     64          // chunks per matrix (PB=128 regressed: short runs re-amplified writes)
#define NBKT   196         // row-buckets per matrix (rows>>shift, shift 8 or 9 -> max bucket 195)
#define NBKH   98          // NBKT/2: each hist/scat block owns half the buckets (z=2)
#define SCANN  (4 * NBKT * PB)   // 50176 counters (+1 sentinel)

static inline int ceil_div(int a, int b) { return (a + b - 1) / b; }

typedef unsigned int uint32;

// ---- bf16 helpers: rows stored as packed pairs (uint32 = 2 bf16, little-endian) ----
__device__ __forceinline__ float bfLO(uint32 u) { return __uint_as_float(u << 16); }
__device__ __forceinline__ float bfHI(uint32 u) { return __uint_as_float(u & 0xffff0000u); }
__device__ __forceinline__ uint32 bf16_rne(float f) {
    uint32 u = __float_as_uint(f);
    return (u + 0x7fffu + ((u >> 16) & 1u)) >> 16;
}
__device__ __forceinline__ uint32 bfPACK(float a, float b) {
    return bf16_rne(a) | (bf16_rne(b) << 16);
}
// ---- packed ELL entry: vals uniform [0,1) -> sign bit 0 -> 15-bit bf16; col fits 17 bits.
// entry 0 == (col 0, val +0.0) -> usable as an exact no-op pad.
__device__ __forceinline__ uint32 csrPACK(int col, float val) {
    return ((uint32)col) | (bf16_rne(val) << 17);
}
__device__ __forceinline__ int   csrCOL(uint32 e) { return (int)(e & 0x1FFFFu); }
__device__ __forceinline__ float csrVAL(uint32 e) { return __uint_as_float((e >> 17) << 16); }

// per-matrix constants: tar(0), src(1), up(2), pu(3)
__device__ __constant__ const int c_nrows[4]  = { NEDGE, NPOI, NUSER, NPOI };
__device__ __constant__ const int c_cntoff[4] = { 0, NEDGE, NEDGE + NPOI, NEDGE + NPOI + NUSER };
__device__ __constant__ const int c_cap[4]    = { 64, 48, 64, 48 };
__device__ __constant__ const int c_shift[4]  = { 8, 9, 8, 9 };   // rows-per-bucket 256 / 512
__device__ __constant__ const long long c_elloff[4] = { 0, 3200000, 8000000, 11200000 };
// total ELL entries = 16,000,000 (64 MB)

// =============== ELL build: bucketed counting sort (4 passes, no global atomics) ===============
// histH/scatS are z-split (z=2): each block scans the whole chunk but owns HALF the
// bucket cursors -> 512 blocks of 1024 thr = 2 blocks/CU (round-12 ran 1/CU, 33% occ).

// Pass H: per-(matrix, chunk) histogram over row-buckets.  histG[(m*NBKT+b)*PB + p]
__global__ __launch_bounds__(1024) void histH_kernel(
    const int* __restrict__ r0, const int* __restrict__ r1,
    const int* __restrict__ r2, const int* __restrict__ r3,
    int* __restrict__ histG) {
    __shared__ int h[NBKH];
    int m = blockIdx.y, p = blockIdx.x, z = blockIdx.z;
    int blo = z * NBKH;
    for (int i = threadIdx.x; i < NBKH; i += 1024) h[i] = 0;
    __syncthreads();
    const int* r = (m == 0) ? r0 : (m == 1) ? r1 : (m == 2) ? r2 : r3;
    int shift = c_shift[m];
    int lo = (int)(((long long)NNZC * p) >> 6);        // PB == 64
    int hi = (int)(((long long)NNZC * (p + 1)) >> 6);
    for (int i = lo + (int)threadIdx.x; i < hi; i += 1024) {
        int b = r[i] >> shift;
        if (b >= blo && b < blo + NBKH) atomicAdd(&h[b - blo], 1);
    }
    __syncthreads();
    for (int b = threadIdx.x; b < NBKH; b += 1024)
        histG[(m * NBKT + blo + b) * PB + p] = h[b];
}

// Pass X: in-place exclusive scan of the 50176 counters (+ sentinel total at [SCANN]).
// Compile-time trip count (round-8 lesson: runtime trip count -> no unroll -> 88us).
__global__ __launch_bounds__(256) void scan_kernel(int* __restrict__ g) {
    __shared__ int base[257];
    int t = threadIdx.x;
    const int chunk = SCANN / 256;   // 196
    int lo = t * chunk;
    int s = 0;
    for (int i = 0; i < chunk; i++) s += g[lo + i];
    base[t + 1] = s;
    __syncthreads();
    if (t == 0) {
        base[0] = 0;
        for (int i = 1; i <= 256; i++) base[i] += base[i - 1];
    }
    __syncthreads();
    int off = base[t];
    for (int i = 0; i < chunk; i++) { int v = g[lo + i]; g[lo + i] = off; off += v; }
    if (t == 255) g[SCANN] = base[256];
}

// Pass S: scatter (row, packed entry) records into exclusive dense ranges (bucket-major).
// z-split: block owns buckets [z*98,(z+1)*98); runs stay whole (one writer per run).
__global__ __launch_bounds__(1024) void scatS_kernel(
    const int* __restrict__ r0, const int* __restrict__ r1,
    const int* __restrict__ r2, const int* __restrict__ r3,
    const int* __restrict__ c0, const int* __restrict__ c1,
    const int* __restrict__ c2, const int* __restrict__ c3,
    const float* __restrict__ v0, const float* __restrict__ v1,
    const float* __restrict__ v2, const float* __restrict__ v3,
    const int* __restrict__ scanG, uint2* __restrict__ rec) {
    __shared__ int cur[NBKH];
    int m = blockIdx.y, p = blockIdx.x, z = blockIdx.z;
    int blo = z * NBKH;
    for (int b = threadIdx.x; b < NBKH; b += 1024)
        cur[b] = scanG[(m * NBKT + blo + b) * PB + p];
    __syncthreads();
    const int*   r = (m == 0) ? r0 : (m == 1) ? r1 : (m == 2) ? r2 : r3;
    const int*   c = (m == 0) ? c0 : (m == 1) ? c1 : (m == 2) ? c2 : c3;
    const float* v = (m == 0) ? v0 : (m == 1) ? v1 : (m == 2) ? v2 : v3;
    int shift = c_shift[m];
    int lo = (int)(((long long)NNZC * p) >> 6);
    int hi = (int)(((long long)NNZC * (p + 1)) >> 6);
    for (int i = lo + (int)threadIdx.x; i < hi; i += 1024) {
        int row = r[i];
        int b = row >> shift;
        if (b >= blo && b < blo + NBKH) {
            int pos = atomicAdd(&cur[b - blo], 1);
            rec[pos] = make_uint2((uint32)row, csrPACK(c[i], v[i]));
        }
    }
}

// Pass B: one block per (matrix, bucket).  Bucket rows are block-exclusive -> LDS row
// counters; ELL scatter confined to a 64-96 KB L2-resident region.  Rows zero-padded
// to the next multiple of 8 so the spmm runs one uniform 8-wide loop (no serial tail).
__global__ __launch_bounds__(512) void fillB_kernel(
    const int* __restrict__ scanG, const uint2* __restrict__ rec,
    int* __restrict__ counts_all, uint32* __restrict__ ell) {
    __shared__ int cnt[512];
    int bx = (int)blockIdx.x;
    int m = bx / NBKT, b = bx - m * NBKT;
    int shift = c_shift[m];
    int rowlo = b << shift;
    int bklen = 1 << shift;
    for (int i = threadIdx.x; i < bklen; i += 512) cnt[i] = 0;
    __syncthreads();
    int lo = scanG[(m * NBKT + b) * PB];
    int hi = scanG[(m * NBKT + b + 1) * PB];   // b=195,m=3 -> scanG[SCANN] sentinel
    int cap = c_cap[m];
    uint32* ebase = ell + c_elloff[m];
    for (int i = lo + (int)threadIdx.x; i < hi; i += 512) {
        uint2 e = rec[i];
        int row = (int)e.x;
        int pos = atomicAdd(&cnt[row - rowlo], 1);
        ebase[(size_t)row * cap + pos] = e.y;
    }
    __syncthreads();
    int nrows_b = c_nrows[m] - rowlo;
    if (nrows_b > bklen) nrows_b = bklen;
    int* counts = counts_all + c_cntoff[m];
    for (int i = threadIdx.x; i < nrows_b; i += 512) {
        int ci = cnt[i];
        counts[rowlo + i] = ci;
        int pad = (ci + 7) & ~7;               // <= cap (cap is a multiple of 8)
        uint32* erow = ebase + (size_t)(rowlo + i) * cap;
        for (int j = ci; j < pad; j++) erow[j] = 0;   // exact no-op entries
    }
}

// ---------------- fused: fp32->bf16 cast of pois + softmax of the attention vecs ----------------
__global__ __launch_bounds__(256) void cast_soft_kernel(
    const float* __restrict__ src, uint32* __restrict__ dst,
    const float* __restrict__ adi, const float* __restrict__ amv,
    float* __restrict__ w) {
    int bx = (int)blockIdx.x;
    if (bx < 25000) {   // 25000*256 == NPOI*64 exactly
        int i = bx * 256 + (int)threadIdx.x;
        float2 f = *(const float2*)(src + (size_t)i * 2);
        dst[i] = bfPACK(f.x, f.y);
        return;
    }
    if (threadIdx.x == 0) {
        for (int b = 0; b < 2; b++) {
            const float* a = b ? amv : adi;
            float m = a[0];
            for (int l = 1; l < 4; l++) m = fmaxf(m, a[l]);
            float e[4]; float s = 0.f;
            for (int l = 0; l < 4; l++) { e[l] = __expf(a[l] - m); s += e[l]; }
            for (int l = 0; l < 4; l++) w[b * 4 + l] = e[l] / s;
        }
    }
}

// ---- 8-FMA helper: one scalar entry value v against a 16B (8 bf16) operand slice ----
__device__ __forceinline__ void fma8(float2& a0, float2& a1, float2& a2, float2& a3,
                                     float v, uint4 u) {
    a0.x = fmaf(v, bfLO(u.x), a0.x); a0.y = fmaf(v, bfHI(u.x), a0.y);
    a1.x = fmaf(v, bfLO(u.y), a1.x); a1.y = fmaf(v, bfHI(u.y), a1.y);
    a2.x = fmaf(v, bfLO(u.z), a2.x); a2.y = fmaf(v, bfHI(u.z), a2.y);
    a3.x = fmaf(v, bfLO(u.w), a3.x); a3.y = fmaf(v, bfHI(u.w), a3.y);
}

// ---------------- hop1 SpMM: y_bf[row] = A @ x_bf ----------------
// 16-lane group per row: lane t gathers uint4 (16B = 8 bf16) of the 256B operand row.
// Single uniform 8-wide loop over the zero-padded count (pad entries are exact no-ops).
template<int CAP>
__global__ __launch_bounds__(256) void spmm1_kernel(
    const int* __restrict__ counts, const uint32* __restrict__ ell,
    const uint32* __restrict__ xbf, uint32* __restrict__ ybf, int n_rows) {
    int row = (int)((blockIdx.x * blockDim.x + threadIdx.x) >> 4);
    int t   = (int)(threadIdx.x & 15);
    if (row >= n_rows) return;
    int pad = (counts[row] + 7) & ~7;
    const uint32* erow = ell + (size_t)row * CAP;
    float2 a0 = {0.f,0.f}, a1 = {0.f,0.f}, a2 = {0.f,0.f}, a3 = {0.f,0.f};
    for (int j = 0; j < pad; j += 8) {
        uint4 qa = *(const uint4*)(erow + j);
        uint4 qb = *(const uint4*)(erow + j + 4);
        uint4 u0 = *((const uint4*)(xbf + (size_t)csrCOL(qa.x) * 64) + t);
        uint4 u1 = *((const uint4*)(xbf + (size_t)csrCOL(qa.y) * 64) + t);
        uint4 u2 = *((const uint4*)(xbf + (size_t)csrCOL(qa.z) * 64) + t);
        uint4 u3 = *((const uint4*)(xbf + (size_t)csrCOL(qa.w) * 64) + t);
        uint4 u4 = *((const uint4*)(xbf + (size_t)csrCOL(qb.x) * 64) + t);
        uint4 u5 = *((const uint4*)(xbf + (size_t)csrCOL(qb.y) * 64) + t);
        uint4 u6 = *((const uint4*)(xbf + (size_t)csrCOL(qb.z) * 64) + t);
        uint4 u7 = *((const uint4*)(xbf + (size_t)csrCOL(qb.w) * 64) + t);
        fma8(a0,a1,a2,a3, csrVAL(qa.x), u0); fma8(a0,a1,a2,a3, csrVAL(qa.y), u1);
        fma8(a0,a1,a2,a3, csrVAL(qa.z), u2); fma8(a0,a1,a2,a3, csrVAL(qa.w), u3);
        fma8(a0,a1,a2,a3, csrVAL(qb.x), u4); fma8(a0,a1,a2,a3, csrVAL(qb.y), u5);
        fma8(a0,a1,a2,a3, csrVAL(qb.z), u6); fma8(a0,a1,a2,a3, csrVAL(qb.w), u7);
    }
    uint4 o;
    o.x = bfPACK(a0.x, a0.y); o.y = bfPACK(a1.x, a1.y);
    o.z = bfPACK(a2.x, a2.y); o.w = bfPACK(a3.x, a3.y);
    *((uint4*)(ybf + (size_t)row * 64) + t) = o;
}

// ---------------- hop2: xnew = relu(A@m)+xin, padded ELL ----------------
// MODE 0: write xnew (bf16) to xoutbf                       (layers 1,2)
// MODE 1: fused epi1: out = (w0+w4)*pois_bf + w1*x1 + w2*x2 + w3*x3   (branch-0 layer 3)
// MODE 2: fused epi2: out += w5*x1 + w6*x2 + w7*x3                    (branch-1 layer 3)
// x3 stays in fp32 registers in MODE 1/2.  MODE1 reads bf16 pois (round-13: -25.6MB).
template<int CAP, int MODE>
__global__ __launch_bounds__(256) void spmm2_kernel(
    const int* __restrict__ counts, const uint32* __restrict__ ell,
    const uint32* __restrict__ mbf, const uint32* __restrict__ xinbf,
    uint32* __restrict__ xoutbf, const uint32* __restrict__ x1bf,
    const uint32* __restrict__ poisbf, const float* __restrict__ w,
    float* __restrict__ outf, int n_rows) {
    int row = (int)((blockIdx.x * blockDim.x + threadIdx.x) >> 4);
    int t   = (int)(threadIdx.x & 15);
    if (row >= n_rows) return;
    int pad = (counts[row] + 7) & ~7;
    const uint32* erow = ell + (size_t)row * CAP;
    float2 a0 = {0.f,0.f}, a1 = {0.f,0.f}, a2 = {0.f,0.f}, a3 = {0.f,0.f};
    for (int j = 0; j < pad; j += 8) {
        uint4 qa = *(const uint4*)(erow + j);
        uint4 qb = *(const uint4*)(erow + j + 4);
        uint4 u0 = *((const uint4*)(mbf + (size_t)csrCOL(qa.x) * 64) + t);
        uint4 u1 = *((const uint4*)(mbf + (size_t)csrCOL(qa.y) * 64) + t);
        uint4 u2 = *((const uint4*)(mbf + (size_t)csrCOL(qa.z) * 64) + t);
        uint4 u3 = *((const uint4*)(mbf + (size_t)csrCOL(qa.w) * 64) + t);
        uint4 u4 = *((const uint4*)(mbf + (size_t)csrCOL(qb.x) * 64) + t);
        uint4 u5 = *((const uint4*)(mbf + (size_t)csrCOL(qb.y) * 64) + t);
        uint4 u6 = *((const uint4*)(mbf + (size_t)csrCOL(qb.z) * 64) + t);
        uint4 u7 = *((const uint4*)(mbf + (size_t)csrCOL(qb.w) * 64) + t);
        fma8(a0,a1,a2,a3, csrVAL(qa.x), u0); fma8(a0,a1,a2,a3, csrVAL(qa.y), u1);
        fma8(a0,a1,a2,a3, csrVAL(qa.z), u2); fma8(a0,a1,a2,a3, csrVAL(qa.w), u3);
        fma8(a0,a1,a2,a3, csrVAL(qb.x), u4); fma8(a0,a1,a2,a3, csrVAL(qb.y), u5);
        fma8(a0,a1,a2,a3, csrVAL(qb.z), u6); fma8(a0,a1,a2,a3, csrVAL(qb.w), u7);
    }
    uint4 ui = *((const uint4*)(xinbf + (size_t)row * 64) + t);   // x2 (or x_{l-1})
    float x2v[8] = { bfLO(ui.x), bfHI(ui.x), bfLO(ui.y), bfHI(ui.y),
                     bfLO(ui.z), bfHI(ui.z), bfLO(ui.w), bfHI(ui.w) };
    float x3v[8] = { fmaxf(a0.x,0.f)+x2v[0], fmaxf(a0.y,0.f)+x2v[1],
                     fmaxf(a1.x,0.f)+x2v[2], fmaxf(a1.y,0.f)+x2v[3],
                     fmaxf(a2.x,0.f)+x2v[4], fmaxf(a2.y,0.f)+x2v[5],
                     fmaxf(a3.x,0.f)+x2v[6], fmaxf(a3.y,0.f)+x2v[7] };
    if (MODE == 0) {
        uint4 o;
        o.x = bfPACK(x3v[0], x3v[1]); o.y = bfPACK(x3v[2], x3v[3]);
        o.z = bfPACK(x3v[4], x3v[5]); o.w = bfPACK(x3v[6], x3v[7]);
        *((uint4*)(xoutbf + (size_t)row * 64) + t) = o;
    } else {
        uint4 u1v = *((const uint4*)(x1bf + (size_t)row * 64) + t);
        float x1v[8] = { bfLO(u1v.x), bfHI(u1v.x), bfLO(u1v.y), bfHI(u1v.y),
                         bfLO(u1v.z), bfHI(u1v.z), bfLO(u1v.w), bfHI(u1v.w) };
        float* op = outf + (size_t)row * 128 + t * 8;
        float4 o0, o1;
        if (MODE == 1) {
            float w04 = w[0] + w[4];
            uint4 pb = *((const uint4*)(poisbf + (size_t)row * 64) + t);
            float pv[8] = { bfLO(pb.x), bfHI(pb.x), bfLO(pb.y), bfHI(pb.y),
                            bfLO(pb.z), bfHI(pb.z), bfLO(pb.w), bfHI(pb.w) };
            o0.x = w04*pv[0] + w[1]*x1v[0] + w[2]*x2v[0] + w[3]*x3v[0];
            o0.y = w04*pv[1] + w[1]*x1v[1] + w[2]*x2v[1] + w[3]*x3v[1];
            o0.z = w04*pv[2] + w[1]*x1v[2] + w[2]*x2v[2] + w[3]*x3v[2];
            o0.w = w04*pv[3] + w[1]*x1v[3] + w[2]*x2v[3] + w[3]*x3v[3];
            o1.x = w04*pv[4] + w[1]*x1v[4] + w[2]*x2v[4] + w[3]*x3v[4];
            o1.y = w04*pv[5] + w[1]*x1v[5] + w[2]*x2v[5] + w[3]*x3v[5];
            o1.z = w04*pv[6] + w[1]*x1v[6] + w[2]*x2v[6] + w[3]*x3v[6];
            o1.w = w04*pv[7] + w[1]*x1v[7] + w[2]*x2v[7] + w[3]*x3v[7];
        } else {
            float4 p0 = ((const float4*)op)[0], p1 = ((const float4*)op)[1];
            o0.x = p0.x + w[5]*x1v[0] + w[6]*x2v[0] + w[7]*x3v[0];
            o0.y = p0.y + w[5]*x1v[1] + w[6]*x2v[1] + w[7]*x3v[1];
            o0.z = p0.z + w[5]*x1v[2] + w[6]*x2v[2] + w[7]*x3v[2];
            o0.w = p0.w + w[5]*x1v[3] + w[6]*x2v[3] + w[7]*x3v[3];
            o1.x = p1.x + w[5]*x1v[4] + w[6]*x2v[4] + w[7]*x3v[4];
            o1.y = p1.y + w[5]*x1v[5] + w[6]*x2v[5] + w[7]*x3v[5];
            o1.z = p1.z + w[5]*x1v[6] + w[6]*x2v[6] + w[7]*x3v[6];
            o1.w = p1.w + w[5]*x1v[7] + w[6]*x2v[7] + w[7]*x3v[7];
        }
        ((float4*)op)[0] = o0;
        ((float4*)op)[1] = o1;
    }
}

extern "C" void kernel_launch(void* const* d_in, const int* in_sizes, int n_in,
                              void* d_out, int out_size, void* d_ws, size_t ws_size,
                              hipStream_t stream) {
    const float* pois = (const float*)d_in[0];
    const int*   rows_in[4] = { (const int*)d_in[1], (const int*)d_in[4],
                                (const int*)d_in[7], (const int*)d_in[10] };
    const int*   cols_in[4] = { (const int*)d_in[2], (const int*)d_in[5],
                                (const int*)d_in[8], (const int*)d_in[11] };
    const float* vals_in[4] = { (const float*)d_in[3], (const float*)d_in[6],
                                (const float*)d_in[9], (const float*)d_in[12] };
    const float* attn_di = (const float*)d_in[13];
    const float* attn_mv = (const float*)d_in[14];
    float* out = (float*)d_out;

    const int cnt_off[4] = { 0, NEDGE, NEDGE + NPOI, NEDGE + NPOI + NUSER };
    const long long ell_off[4] = { 0, 3200000, 8000000, 11200000 };
    const int NTOT = NEDGE + NPOI + NUSER + NPOI;  // 300000

    // -------- workspace carve-up (~182 MB, unchanged) --------
    char* p = (char*)d_ws;
    float*  wsoft      = (float*)p;  p += 256;
    int*    counts_all = (int*)p;    p += (size_t)NTOT * 4;
    p = (char*)(((size_t)p + 255) & ~255ull);
    int*    scanG      = (int*)p;    p += (size_t)(SCANN + 64) * 4;  // 50177 + pad
    p = (char*)(((size_t)p + 255) & ~255ull);
    uint32* ell        = (uint32*)p; p += (size_t)16000000 * 4;     // 64 MB ELL
    uint32* mbf        = (uint32*)p; p += (size_t)NEDGE * 64 * 4;   // 12.8 MB
    uint32* poisbf     = (uint32*)p; p += (size_t)NPOI * 64 * 4;    // 25.6 MB
    uint32* xl[3];
    for (int l = 0; l < 3; l++) { xl[l] = (uint32*)p; p += (size_t)NPOI * 64 * 4; }
    // records (32 MB) alias xl[0..1] (51.2 MB): consumed by fillB before spmm writes xl.
    uint2* rec = (uint2*)xl[0];
    (void)ws_size; (void)out_size; (void)n_in; (void)in_sizes;

    // -------- ELL build: hist -> scan -> scatter-sort -> bucket fill (+pad) --------
    histH_kernel<<<dim3(PB, 4, 2), 1024, 0, stream>>>(
        rows_in[0], rows_in[1], rows_in[2], rows_in[3], scanG);
    scan_kernel<<<1, 256, 0, stream>>>(scanG);
    scatS_kernel<<<dim3(PB, 4, 2), 1024, 0, stream>>>(
        rows_in[0], rows_in[1], rows_in[2], rows_in[3],
        cols_in[0], cols_in[1], cols_in[2], cols_in[3],
        vals_in[0], vals_in[1], vals_in[2], vals_in[3],
        scanG, rec);
    fillB_kernel<<<4 * NBKT, 512, 0, stream>>>(scanG, rec, counts_all, ell);

    // -------- fused cast(pois->bf16) + softmax --------
    cast_soft_kernel<<<25000 + 1, 256, 0, stream>>>(pois, poisbf, attn_di, attn_mv, wsoft);

    // -------- two branches, 3 layers each; epilogue fused into layer-3 spmm2 --------
    for (int br = 0; br < 2; br++) {
        int m1i = br ? 2 : 0;   // up  : tar   (50k rows, CAP 64)
        int m2i = br ? 3 : 1;   // pu  : src   (100k rows, CAP 48)
        const int* cn1 = counts_all + cnt_off[m1i];
        const int* cn2 = counts_all + cnt_off[m2i];
        const uint32* el1 = ell + ell_off[m1i];
        const uint32* el2 = ell + ell_off[m2i];
        const int n1 = 50000;  // NEDGE == NUSER
        const uint32* xcur = poisbf;
        for (int l = 1; l <= NL; l++) {
            spmm1_kernel<64><<<ceil_div(n1, 16), 256, 0, stream>>>(cn1, el1, xcur, mbf, n1);
            if (l < NL) {
                spmm2_kernel<48, 0><<<ceil_div(NPOI, 16), 256, 0, stream>>>(
                    cn2, el2, mbf, xcur, xl[l - 1], nullptr, nullptr, wsoft, nullptr, NPOI);
                xcur = xl[l - 1];
            } else if (br == 0) {
                spmm2_kernel<48, 1><<<ceil_div(NPOI, 16), 256, 0, stream>>>(
                    cn2, el2, mbf, xcur, nullptr, xl[0], poisbf, wsoft, out, NPOI);
            } else {
                spmm2_kernel<48, 2><<<ceil_div(NPOI, 16), 256, 0, stream>>>(
                    cn2, el2, mbf, xcur, nullptr, xl[0], nullptr, wsoft, out, NPOI);
            }
        }
    }
}

// Round 14
// 699.105 us; speedup vs baseline: 1.0532x; 1.0532x over previous
//
#include <hip/hip_runtime.h>

#define NNZC   1000000
#define NPOI   100000
#define NEDGE  50000
#define NUSER  50000
#define DIM    128
#define NL     3

#define PB     64          // chunks per matrix
#define NBKT   196         // row-buckets per matrix (rows>>shift, shift 8 or 9)
#define SCANN  (4 * NBKT * PB)   // 50176 counters (+1 sentinel)

static inline int ceil_div(int a, int b) { return (a + b - 1) / b; }

typedef unsigned int uint32;

// ---- bf16 helpers ----
__device__ __forceinline__ float bfLO(uint32 u) { return __uint_as_float(u << 16); }
__device__ __forceinline__ float bfHI(uint32 u) { return __uint_as_float(u & 0xffff0000u); }
__device__ __forceinline__ uint32 bf16_rne(float f) {
    uint32 u = __float_as_uint(f);
    return (u + 0x7fffu + ((u >> 16) & 1u)) >> 16;
}
__device__ __forceinline__ uint32 bfPACK(float a, float b) {
    return bf16_rne(a) | (bf16_rne(b) << 16);
}
// packed ELL entry: val in [0,1) -> 15-bit bf16; col fits 17 bits (max 99999 after bake).
// entry 0 == (col 0, val +0.0) -> exact no-op pad.
__device__ __forceinline__ uint32 csrPACK(int col, float val) {
    return ((uint32)col) | (bf16_rne(val) << 17);
}
__device__ __forceinline__ int   csrCOL(uint32 e) { return (int)(e & 0x1FFFFu); }
__device__ __forceinline__ float csrVAL(uint32 e) { return __uint_as_float((e >> 17) << 16); }

// per-matrix constants: tar(0), src(1), up(2), pu(3)
__device__ __constant__ const int c_nrows[4]  = { NEDGE, NPOI, NUSER, NPOI };
__device__ __constant__ const int c_cntoff[4] = { 0, NEDGE, NEDGE + NPOI, NEDGE + NPOI + NUSER };
__device__ __constant__ const int c_cap[4]    = { 64, 48, 64, 48 };
__device__ __constant__ const int c_shift[4]  = { 8, 9, 8, 9 };
__device__ __constant__ const int c_coloff[4] = { 0, 0, 0, 50000 };  // pu cols baked +50000
__device__ __constant__ const long long c_elloff[4] = { 0, 3200000, 8000000, 11200000 };

// =============== ELL build: bucketed counting sort (round-12 form, z-split reverted) ==========

__global__ __launch_bounds__(1024) void histH_kernel(
    const int* __restrict__ r0, const int* __restrict__ r1,
    const int* __restrict__ r2, const int* __restrict__ r3,
    int* __restrict__ histG) {
    __shared__ int h[NBKT];
    int m = blockIdx.y, p = blockIdx.x;
    for (int i = threadIdx.x; i < NBKT; i += 1024) h[i] = 0;
    __syncthreads();
    const int* r = (m == 0) ? r0 : (m == 1) ? r1 : (m == 2) ? r2 : r3;
    int shift = c_shift[m];
    int lo = (int)(((long long)NNZC * p) >> 6);
    int hi = (int)(((long long)NNZC * (p + 1)) >> 6);
    for (int i = lo + (int)threadIdx.x; i < hi; i += 1024)
        atomicAdd(&h[r[i] >> shift], 1);
    __syncthreads();
    for (int b = threadIdx.x; b < NBKT; b += 1024)
        histG[(m * NBKT + b) * PB + p] = h[b];
}

// compile-time trip count (round-8 lesson)
__global__ __launch_bounds__(256) void scan_kernel(int* __restrict__ g) {
    __shared__ int base[257];
    int t = threadIdx.x;
    const int chunk = SCANN / 256;   // 196
    int lo = t * chunk;
    int s = 0;
    for (int i = 0; i < chunk; i++) s += g[lo + i];
    base[t + 1] = s;
    __syncthreads();
    if (t == 0) {
        base[0] = 0;
        for (int i = 1; i <= 256; i++) base[i] += base[i - 1];
    }
    __syncthreads();
    int off = base[t];
    for (int i = 0; i < chunk; i++) { int v = g[lo + i]; g[lo + i] = off; off += v; }
    if (t == 255) g[SCANN] = base[256];
}

__global__ __launch_bounds__(1024) void scatS_kernel(
    const int* __restrict__ r0, const int* __restrict__ r1,
    const int* __restrict__ r2, const int* __restrict__ r3,
    const int* __restrict__ c0, const int* __restrict__ c1,
    const int* __restrict__ c2, const int* __restrict__ c3,
    const float* __restrict__ v0, const float* __restrict__ v1,
    const float* __restrict__ v2, const float* __restrict__ v3,
    const int* __restrict__ scanG, uint2* __restrict__ rec) {
    __shared__ int cur[NBKT];
    int m = blockIdx.y, p = blockIdx.x;
    for (int b = threadIdx.x; b < NBKT; b += 1024)
        cur[b] = scanG[(m * NBKT + b) * PB + p];
    __syncthreads();
    const int*   r = (m == 0) ? r0 : (m == 1) ? r1 : (m == 2) ? r2 : r3;
    const int*   c = (m == 0) ? c0 : (m == 1) ? c1 : (m == 2) ? c2 : c3;
    const float* v = (m == 0) ? v0 : (m == 1) ? v1 : (m == 2) ? v2 : v3;
    int shift = c_shift[m];
    int coff  = c_coloff[m];
    int lo = (int)(((long long)NNZC * p) >> 6);
    int hi = (int)(((long long)NNZC * (p + 1)) >> 6);
    for (int i = lo + (int)threadIdx.x; i < hi; i += 1024) {
        int row = r[i];
        int pos = atomicAdd(&cur[row >> shift], 1);
        rec[pos] = make_uint2((uint32)row, csrPACK(c[i] + coff, v[i]));
    }
}

__global__ __launch_bounds__(512) void fillB_kernel(
    const int* __restrict__ scanG, const uint2* __restrict__ rec,
    int* __restrict__ counts_all, uint32* __restrict__ ell) {
    __shared__ int cnt[512];
    int bx = (int)blockIdx.x;
    int m = bx / NBKT, b = bx - m * NBKT;
    int shift = c_shift[m];
    int rowlo = b << shift;
    int bklen = 1 << shift;
    for (int i = threadIdx.x; i < bklen; i += 512) cnt[i] = 0;
    __syncthreads();
    int lo = scanG[(m * NBKT + b) * PB];
    int hi = scanG[(m * NBKT + b + 1) * PB];
    int cap = c_cap[m];
    uint32* ebase = ell + c_elloff[m];
    for (int i = lo + (int)threadIdx.x; i < hi; i += 512) {
        uint2 e = rec[i];
        int row = (int)e.x;
        int pos = atomicAdd(&cnt[row - rowlo], 1);
        ebase[(size_t)row * cap + pos] = e.y;
    }
    __syncthreads();
    int nrows_b = c_nrows[m] - rowlo;
    if (nrows_b > bklen) nrows_b = bklen;
    int* counts = counts_all + c_cntoff[m];
    for (int i = threadIdx.x; i < nrows_b; i += 512) {
        int ci = cnt[i];
        counts[rowlo + i] = ci;
        int pad = (ci + 7) & ~7;
        uint32* erow = ebase + (size_t)(rowlo + i) * cap;
        for (int j = ci; j < pad; j++) erow[j] = 0;   // exact no-op entries
    }
}

// ---------------- fused cast(pois->bf16) + softmax ----------------
__global__ __launch_bounds__(256) void cast_soft_kernel(
    const float* __restrict__ src, uint32* __restrict__ dst,
    const float* __restrict__ adi, const float* __restrict__ amv,
    float* __restrict__ w) {
    int bx = (int)blockIdx.x;
    if (bx < 25000) {
        int i = bx * 256 + (int)threadIdx.x;
        float2 f = *(const float2*)(src + (size_t)i * 2);
        dst[i] = bfPACK(f.x, f.y);
        return;
    }
    if (threadIdx.x == 0) {
        for (int b = 0; b < 2; b++) {
            const float* a = b ? amv : adi;
            float m = a[0];
            for (int l = 1; l < 4; l++) m = fmaxf(m, a[l]);
            float e[4]; float s = 0.f;
            for (int l = 0; l < 4; l++) { e[l] = __expf(a[l] - m); s += e[l]; }
            for (int l = 0; l < 4; l++) w[b * 4 + l] = e[l] / s;
        }
    }
}

// ---- shared 8-wide gather-FMA loop over a zero-padded ELL row ----
__device__ __forceinline__ void fma8(float2& a0, float2& a1, float2& a2, float2& a3,
                                     float v, uint4 u) {
    a0.x = fmaf(v, bfLO(u.x), a0.x); a0.y = fmaf(v, bfHI(u.x), a0.y);
    a1.x = fmaf(v, bfLO(u.y), a1.x); a1.y = fmaf(v, bfHI(u.y), a1.y);
    a2.x = fmaf(v, bfLO(u.z), a2.x); a2.y = fmaf(v, bfHI(u.z), a2.y);
    a3.x = fmaf(v, bfLO(u.w), a3.x); a3.y = fmaf(v, bfHI(u.w), a3.y);
}
__device__ __forceinline__ void gather8(const uint32* __restrict__ erow, int pad,
                                        const uint32* __restrict__ x, int t,
                                        float2& a0, float2& a1, float2& a2, float2& a3) {
    for (int j = 0; j < pad; j += 8) {
        uint4 qa = *(const uint4*)(erow + j);
        uint4 qb = *(const uint4*)(erow + j + 4);
        uint4 u0 = *((const uint4*)(x + (size_t)csrCOL(qa.x) * 64) + t);
        uint4 u1 = *((const uint4*)(x + (size_t)csrCOL(qa.y) * 64) + t);
        uint4 u2 = *((const uint4*)(x + (size_t)csrCOL(qa.z) * 64) + t);
        uint4 u3 = *((const uint4*)(x + (size_t)csrCOL(qa.w) * 64) + t);
        uint4 u4 = *((const uint4*)(x + (size_t)csrCOL(qb.x) * 64) + t);
        uint4 u5 = *((const uint4*)(x + (size_t)csrCOL(qb.y) * 64) + t);
        uint4 u6 = *((const uint4*)(x + (size_t)csrCOL(qb.z) * 64) + t);
        uint4 u7 = *((const uint4*)(x + (size_t)csrCOL(qb.w) * 64) + t);
        fma8(a0,a1,a2,a3, csrVAL(qa.x), u0); fma8(a0,a1,a2,a3, csrVAL(qa.y), u1);
        fma8(a0,a1,a2,a3, csrVAL(qa.z), u2); fma8(a0,a1,a2,a3, csrVAL(qa.w), u3);
        fma8(a0,a1,a2,a3, csrVAL(qb.x), u4); fma8(a0,a1,a2,a3, csrVAL(qb.y), u5);
        fma8(a0,a1,a2,a3, csrVAL(qb.z), u6); fma8(a0,a1,a2,a3, csrVAL(qb.w), u7);
    }
}
__device__ __forceinline__ void unp8(uint4 u, float* o) {
    o[0]=bfLO(u.x); o[1]=bfHI(u.x); o[2]=bfLO(u.y); o[3]=bfHI(u.y);
    o[4]=bfLO(u.z); o[5]=bfHI(u.z); o[6]=bfLO(u.w); o[7]=bfHI(u.w);
}

// ---------------- hop1, branch-merged: rows [0,n0) side A, [n0,ntot) side B ----------------
__global__ __launch_bounds__(256) void spmm1M_kernel(
    const int* __restrict__ cntA, const uint32* __restrict__ ellA, const uint32* __restrict__ xA,
    const int* __restrict__ cntB, const uint32* __restrict__ ellB, const uint32* __restrict__ xB,
    uint32* __restrict__ ybf, int n0, int ntot) {
    int row = (int)((blockIdx.x * blockDim.x + threadIdx.x) >> 4);
    int t   = (int)(threadIdx.x & 15);
    if (row >= ntot) return;
    const int* cnt; const uint32* ell; const uint32* x; int lr;
    if (row < n0) { cnt = cntA; ell = ellA; x = xA; lr = row; }
    else          { cnt = cntB; ell = ellB; x = xB; lr = row - n0; }
    int pad = (cnt[lr] + 7) & ~7;
    const uint32* erow = ell + (size_t)lr * 64;
    float2 a0 = {0.f,0.f}, a1 = {0.f,0.f}, a2 = {0.f,0.f}, a3 = {0.f,0.f};
    gather8(erow, pad, x, t, a0, a1, a2, a3);
    uint4 o;
    o.x = bfPACK(a0.x, a0.y); o.y = bfPACK(a1.x, a1.y);
    o.z = bfPACK(a2.x, a2.y); o.w = bfPACK(a3.x, a3.y);
    *((uint4*)(ybf + (size_t)row * 64) + t) = o;
}

// ---------------- hop2 layers 1-2, branch-merged (gather from shared mbfM) ----------------
__global__ __launch_bounds__(256) void spmm2M_kernel(
    const int* __restrict__ cntA, const uint32* __restrict__ ellA,
    const uint32* __restrict__ xinA, uint32* __restrict__ xoutA,
    const int* __restrict__ cntB, const uint32* __restrict__ ellB,
    const uint32* __restrict__ xinB, uint32* __restrict__ xoutB,
    const uint32* __restrict__ gbase, int n0, int ntot) {
    int row = (int)((blockIdx.x * blockDim.x + threadIdx.x) >> 4);
    int t   = (int)(threadIdx.x & 15);
    if (row >= ntot) return;
    const int* cnt; const uint32* ell; const uint32* xin; uint32* xout; int lr;
    if (row < n0) { cnt = cntA; ell = ellA; xin = xinA; xout = xoutA; lr = row; }
    else          { cnt = cntB; ell = ellB; xin = xinB; xout = xoutB; lr = row - n0; }
    int pad = (cnt[lr] + 7) & ~7;
    const uint32* erow = ell + (size_t)lr * 48;
    float2 a0 = {0.f,0.f}, a1 = {0.f,0.f}, a2 = {0.f,0.f}, a3 = {0.f,0.f};
    gather8(erow, pad, gbase, t, a0, a1, a2, a3);
    uint4 ui = *((const uint4*)(xin + (size_t)lr * 64) + t);
    float xi[8]; unp8(ui, xi);
    uint4 o;
    o.x = bfPACK(fmaxf(a0.x,0.f)+xi[0], fmaxf(a0.y,0.f)+xi[1]);
    o.y = bfPACK(fmaxf(a1.x,0.f)+xi[2], fmaxf(a1.y,0.f)+xi[3]);
    o.z = bfPACK(fmaxf(a2.x,0.f)+xi[4], fmaxf(a2.y,0.f)+xi[5]);
    o.w = bfPACK(fmaxf(a3.x,0.f)+xi[6], fmaxf(a3.y,0.f)+xi[7]);
    *((uint4*)(xout + (size_t)lr * 64) + t) = o;
}

// ---------------- fused layer-3: both branches' gathers + full epilogue, one pass ----------------
__global__ __launch_bounds__(256) void spmm2F_kernel(
    const int* __restrict__ cntS, const uint32* __restrict__ ellS,
    const int* __restrict__ cntP, const uint32* __restrict__ ellP,
    const uint32* __restrict__ gbase,
    const uint32* __restrict__ x1A, const uint32* __restrict__ x2A,
    const uint32* __restrict__ x1B, const uint32* __restrict__ x2B,
    const uint32* __restrict__ poisbf, const float* __restrict__ w,
    float* __restrict__ out, int n) {
    int row = (int)((blockIdx.x * blockDim.x + threadIdx.x) >> 4);
    int t   = (int)(threadIdx.x & 15);
    if (row >= n) return;
    // branch 0 (src)
    float2 a0={0,0}, a1={0,0}, a2={0,0}, a3={0,0};
    gather8(ellS + (size_t)row * 48, (cntS[row] + 7) & ~7, gbase, t, a0, a1, a2, a3);
    float x2a[8]; unp8(*((const uint4*)(x2A + (size_t)row * 64) + t), x2a);
    float x3a[8] = { fmaxf(a0.x,0.f)+x2a[0], fmaxf(a0.y,0.f)+x2a[1],
                     fmaxf(a1.x,0.f)+x2a[2], fmaxf(a1.y,0.f)+x2a[3],
                     fmaxf(a2.x,0.f)+x2a[4], fmaxf(a2.y,0.f)+x2a[5],
                     fmaxf(a3.x,0.f)+x2a[6], fmaxf(a3.y,0.f)+x2a[7] };
    // branch 1 (pu)
    a0={0,0}; a1={0,0}; a2={0,0}; a3={0,0};
    gather8(ellP + (size_t)row * 48, (cntP[row] + 7) & ~7, gbase, t, a0, a1, a2, a3);
    float x2b[8]; unp8(*((const uint4*)(x2B + (size_t)row * 64) + t), x2b);
    float x3b[8] = { fmaxf(a0.x,0.f)+x2b[0], fmaxf(a0.y,0.f)+x2b[1],
                     fmaxf(a1.x,0.f)+x2b[2], fmaxf(a1.y,0.f)+x2b[3],
                     fmaxf(a2.x,0.f)+x2b[4], fmaxf(a2.y,0.f)+x2b[5],
                     fmaxf(a3.x,0.f)+x2b[6], fmaxf(a3.y,0.f)+x2b[7] };
    float x1a[8]; unp8(*((const uint4*)(x1A + (size_t)row * 64) + t), x1a);
    float x1b[8]; unp8(*((const uint4*)(x1B + (size_t)row * 64) + t), x1b);
    float pv[8];  unp8(*((const uint4*)(poisbf + (size_t)row * 64) + t), pv);
    float w04 = w[0] + w[4];
    float* op = out + (size_t)row * 128 + t * 8;
    float4 o0, o1;
    float ov[8];
#pragma unroll
    for (int k = 0; k < 8; k++)
        ov[k] = w04*pv[k] + w[1]*x1a[k] + w[2]*x2a[k] + w[3]*x3a[k]
                          + w[5]*x1b[k] + w[6]*x2b[k] + w[7]*x3b[k];
    o0 = make_float4(ov[0], ov[1], ov[2], ov[3]);
    o1 = make_float4(ov[4], ov[5], ov[6], ov[7]);
    ((float4*)op)[0] = o0;
    ((float4*)op)[1] = o1;
}

// ---------------- fallback layer-3 epilogue (round-12 structure) ----------------
template<int MODE>   // 1: out = w04*pois+..., 2: out += ...
__global__ __launch_bounds__(256) void spmm2E_kernel(
    const int* __restrict__ counts, const uint32* __restrict__ ell,
    const uint32* __restrict__ gbase, const uint32* __restrict__ xinbf,
    const uint32* __restrict__ x1bf, const uint32* __restrict__ poisbf,
    const float* __restrict__ w, float* __restrict__ out, int n) {
    int row = (int)((blockIdx.x * blockDim.x + threadIdx.x) >> 4);
    int t   = (int)(threadIdx.x & 15);
    if (row >= n) return;
    float2 a0={0,0}, a1={0,0}, a2={0,0}, a3={0,0};
    gather8(ell + (size_t)row * 48, (counts[row] + 7) & ~7, gbase, t, a0, a1, a2, a3);
    float x2v[8]; unp8(*((const uint4*)(xinbf + (size_t)row * 64) + t), x2v);
    float x3v[8] = { fmaxf(a0.x,0.f)+x2v[0], fmaxf(a0.y,0.f)+x2v[1],
                     fmaxf(a1.x,0.f)+x2v[2], fmaxf(a1.y,0.f)+x2v[3],
                     fmaxf(a2.x,0.f)+x2v[4], fmaxf(a2.y,0.f)+x2v[5],
                     fmaxf(a3.x,0.f)+x2v[6], fmaxf(a3.y,0.f)+x2v[7] };
    float x1v[8]; unp8(*((const uint4*)(x1bf + (size_t)row * 64) + t), x1v);
    float* op = out + (size_t)row * 128 + t * 8;
    float ov[8];
    if (MODE == 1) {
        float pv[8]; unp8(*((const uint4*)(poisbf + (size_t)row * 64) + t), pv);
        float w04 = w[0] + w[4];
#pragma unroll
        for (int k = 0; k < 8; k++)
            ov[k] = w04*pv[k] + w[1]*x1v[k] + w[2]*x2v[k] + w[3]*x3v[k];
    } else {
        float4 p0 = ((const float4*)op)[0], p1 = ((const float4*)op)[1];
        float pr[8] = { p0.x,p0.y,p0.z,p0.w, p1.x,p1.y,p1.z,p1.w };
#pragma unroll
        for (int k = 0; k < 8; k++)
            ov[k] = pr[k] + w[5]*x1v[k] + w[6]*x2v[k] + w[7]*x3v[k];
    }
    ((float4*)op)[0] = make_float4(ov[0], ov[1], ov[2], ov[3]);
    ((float4*)op)[1] = make_float4(ov[4], ov[5], ov[6], ov[7]);
}

extern "C" void kernel_launch(void* const* d_in, const int* in_sizes, int n_in,
                              void* d_out, int out_size, void* d_ws, size_t ws_size,
                              hipStream_t stream) {
    const float* pois = (const float*)d_in[0];
    const int*   rows_in[4] = { (const int*)d_in[1], (const int*)d_in[4],
                                (const int*)d_in[7], (const int*)d_in[10] };
    const int*   cols_in[4] = { (const int*)d_in[2], (const int*)d_in[5],
                                (const int*)d_in[8], (const int*)d_in[11] };
    const float* vals_in[4] = { (const float*)d_in[3], (const float*)d_in[6],
                                (const float*)d_in[9], (const float*)d_in[12] };
    const float* attn_di = (const float*)d_in[13];
    const float* attn_mv = (const float*)d_in[14];
    float* out = (float*)d_out;

    const int cnt_off[4] = { 0, NEDGE, NEDGE + NPOI, NEDGE + NPOI + NUSER };
    const long long ell_off[4] = { 0, 3200000, 8000000, 11200000 };
    const int NTOT = NEDGE + NPOI + NUSER + NPOI;  // 300000
    const size_t XB = (size_t)NPOI * 64 * 4;       // 25.6 MB (one bf16 x-buffer)

    // -------- carve merged layout (~219 MB); fall back to serial (~181 MB) if it doesn't fit --------
    char* base = (char*)d_ws;
    char* p = base;
    float*  wsoft      = (float*)p;  p += 256;
    int*    counts_all = (int*)p;    p += (size_t)NTOT * 4;
    p = (char*)(((size_t)p + 255) & ~255ull);
    int*    scanG      = (int*)p;    p += (size_t)(SCANN + 64) * 4;
    p = (char*)(((size_t)p + 255) & ~255ull);
    uint32* ell        = (uint32*)p; p += (size_t)16000000 * 4;     // 64 MB
    uint32* poisbf     = (uint32*)p; p += XB;
    char*   varp       = p;          // mode-dependent region starts here

    // merged:   mbfM(100k rows) + xA1 + xA2 + xB1 + xB2   = 5*XB = 128 MB
    // fallback: mbf(50k rows, XB/2) + xl0 + xl1           = 2.5*XB = 64 MB
    bool merged = ((size_t)(varp - base) + 5 * XB) <= ws_size;

    // -------- ELL build (shared; pu cols baked +50000) --------
    uint2* rec = (uint2*)varp;   // 32 MB, consumed by fillB before any x-buffer is written
    histH_kernel<<<dim3(PB, 4), 1024, 0, stream>>>(
        rows_in[0], rows_in[1], rows_in[2], rows_in[3], scanG);
    scan_kernel<<<1, 256, 0, stream>>>(scanG);
    scatS_kernel<<<dim3(PB, 4), 1024, 0, stream>>>(
        rows_in[0], rows_in[1], rows_in[2], rows_in[3],
        cols_in[0], cols_in[1], cols_in[2], cols_in[3],
        vals_in[0], vals_in[1], vals_in[2], vals_in[3],
        scanG, rec);
    fillB_kernel<<<4 * NBKT, 512, 0, stream>>>(scanG, rec, counts_all, ell);
    cast_soft_kernel<<<25000 + 1, 256, 0, stream>>>(pois, poisbf, attn_di, attn_mv, wsoft);

    const int* cn_tar = counts_all + cnt_off[0];
    const int* cn_src = counts_all + cnt_off[1];
    const int* cn_up  = counts_all + cnt_off[2];
    const int* cn_pu  = counts_all + cnt_off[3];
    const uint32* el_tar = ell + ell_off[0];
    const uint32* el_src = ell + ell_off[1];
    const uint32* el_up  = ell + ell_off[2];
    const uint32* el_pu  = ell + ell_off[3];

    if (merged) {
        uint32* mbfM = (uint32*)varp;            // 100k x 64 words
        uint32* xA1  = (uint32*)(varp + 1 * XB);
        uint32* xA2  = (uint32*)(varp + 2 * XB);
        uint32* xB1  = (uint32*)(varp + 3 * XB);
        uint32* xB2  = (uint32*)(varp + 4 * XB);
        // NOTE: rec (32MB) aliases mbfM+xA1 head; fillB finishes before spmm1M writes mbfM.
        const uint32* xa = poisbf; const uint32* xb = poisbf;
        for (int l = 1; l <= NL; l++) {
            spmm1M_kernel<<<ceil_div(2 * NEDGE, 16), 256, 0, stream>>>(
                cn_tar, el_tar, xa, cn_up, el_up, xb, mbfM, NEDGE, 2 * NEDGE);
            if (l < NL) {
                uint32* xoa = (l == 1) ? xA1 : xA2;
                uint32* xob = (l == 1) ? xB1 : xB2;
                spmm2M_kernel<<<ceil_div(2 * NPOI, 16), 256, 0, stream>>>(
                    cn_src, el_src, xa, xoa, cn_pu, el_pu, xb, xob, mbfM, NPOI, 2 * NPOI);
                xa = xoa; xb = xob;
            } else {
                spmm2F_kernel<<<ceil_div(NPOI, 16), 256, 0, stream>>>(
                    cn_src, el_src, cn_pu, el_pu, mbfM,
                    xA1, xA2, xB1, xB2, poisbf, wsoft, out, NPOI);
            }
        }
    } else {
        uint32* mbf = (uint32*)varp;             // 50k x 64 words
        uint32* xl0 = (uint32*)(varp + XB / 2);
        uint32* xl1 = (uint32*)(varp + XB / 2 + XB);
        // pu cols are baked +50000: adjust its gather base so col' indexes mbf correctly.
        const uint32* mbf_pu = mbf - (size_t)NEDGE * 64;
        for (int br = 0; br < 2; br++) {
            const int* cn1 = br ? cn_up : cn_tar;
            const int* cn2 = br ? cn_pu : cn_src;
            const uint32* el1 = br ? el_up : el_tar;
            const uint32* el2 = br ? el_pu : el_src;
            const uint32* gb  = br ? mbf_pu : mbf;
            const uint32* xcur = poisbf;
            for (int l = 1; l <= NL; l++) {
                spmm1M_kernel<<<ceil_div(NEDGE, 16), 256, 0, stream>>>(
                    cn1, el1, xcur, cn1, el1, xcur, mbf, NEDGE, NEDGE);
                if (l < NL) {
                    uint32* xo = (l == 1) ? xl0 : xl1;
                    spmm2M_kernel<<<ceil_div(NPOI, 16), 256, 0, stream>>>(
                        cn2, el2, xcur, xo, cn2, el2, xcur, xo, gb, NPOI, NPOI);
                    xcur = xo;
                } else if (br == 0) {
                    spmm2E_kernel<1><<<ceil_div(NPOI, 16), 256, 0, stream>>>(
                        cn2, el2, gb, xcur, xl0, poisbf, wsoft, out, NPOI);
                } else {
                    spmm2E_kernel<2><<<ceil_div(NPOI, 16), 256, 0, stream>>>(
                        cn2, el2, gb, xcur, xl0, poisbf, wsoft, out, NPOI);
                }
            }
        }
    }
}